// Round 1
// baseline (166.173 us; speedup 1.0000x reference)
//
#include <hip/hip_runtime.h>
#include <math.h>

#define LENGTH   8192
#define CHANNELS 512
#define NSTATE   64
#define TCHUNK   64
#define NCHUNK   (LENGTH / TCHUNK)          /* 128 */
#define E_ELEMS  (NCHUNK * NSTATE * CHANNELS) /* 4,194,304 floats = 16 MB */

// ---------------------------------------------------------------------------
// Setup: Abar[n], CB[n] = C[n]*Bbar[n], AbarT[n] = Abar^TCHUNK  (fp64 precompute)
// Uses rescaled state h' = h / Bbar  =>  h' = Abar*h' + x ;  y = sum CB[n]*h'[n]
// ---------------------------------------------------------------------------
__global__ void k_setup(const float* __restrict__ logA, const float* __restrict__ B,
                        const float* __restrict__ C, float* __restrict__ cons) {
    int n = threadIdx.x;
    if (n < NSTATE) {
        double A    = -exp((double)logA[n]);
        double ab   = exp(A * (1.0 / 4096.0));       // Abar
        double Bbar = (ab - 1.0) * (double)B[n] / A;
        double abT  = ab;
        #pragma unroll
        for (int i = 0; i < 6; ++i) abT *= abT;      // ab^64 == ab^TCHUNK
        cons[n]              = (float)ab;
        cons[NSTATE + n]     = (float)((double)C[n] * Bbar);
        cons[2 * NSTATE + n] = (float)abT;
    }
}

// ---------------------------------------------------------------------------
// Pass 1: per (chunk k, channel c): local end-state from zero init
//   E[k][n][c] = sum_{tau} Abar[n]^(T-1-tau) * x[k*T+tau][c]
// ---------------------------------------------------------------------------
__global__ __launch_bounds__(256) void k_pass1(const float* __restrict__ x,
                                               const float* __restrict__ cons,
                                               float* __restrict__ E) {
    int gtid = blockIdx.x * 256 + threadIdx.x;
    int c = gtid & (CHANNELS - 1);
    int k = gtid >> 9;
    const float* xp = x + (size_t)k * TCHUNK * CHANNELS + c;

    float h[NSTATE];
    #pragma unroll
    for (int n = 0; n < NSTATE; ++n) h[n] = 0.f;

    float xv = xp[0];
    #pragma unroll 2
    for (int tau = 0; tau < TCHUNK; ++tau) {
        float xn = (tau + 1 < TCHUNK) ? xp[(size_t)(tau + 1) * CHANNELS] : 0.f;
        #pragma unroll
        for (int n = 0; n < NSTATE; ++n) h[n] = fmaf(cons[n], h[n], xv);
        xv = xn;
    }

    float* Ep = E + (size_t)k * NSTATE * CHANNELS + c;
    #pragma unroll
    for (int n = 0; n < NSTATE; ++n) Ep[(size_t)n * CHANNELS] = h[n];
}

// ---------------------------------------------------------------------------
// Pass 2: per (state n, channel c): sequential carry scan over chunks, in place.
//   carry[0] = 0 ; carry[k] = AbarT[n]*carry[k-1] + E[k-1]
// Slot k is read (E[k]) before being overwritten with carry[k] -> in-place OK.
// n is uniform per 256-thread block (512 channels per n) -> AbarT is scalar.
// ---------------------------------------------------------------------------
__global__ __launch_bounds__(256) void k_pass2(float* __restrict__ W,
                                               const float* __restrict__ cons) {
    int gtid = blockIdx.x * 256 + threadIdx.x;
    int c = gtid & (CHANNELS - 1);
    int n = gtid >> 9;
    float aT = cons[2 * NSTATE + n];
    float hc = 0.f;
    float* p = W + (size_t)n * CHANNELS + c;
    #pragma unroll 2
    for (int k = 0; k < NCHUNK; ++k) {
        float e = p[(size_t)k * NSTATE * CHANNELS];
        p[(size_t)k * NSTATE * CHANNELS] = hc;
        hc = fmaf(aT, hc, e);
    }
}

// ---------------------------------------------------------------------------
// Pass 3: per (chunk k, channel c): re-scan chunk from exact carry, emit y.
// 4-way split y accumulators keep the dot-product dependency chain short.
// ---------------------------------------------------------------------------
__global__ __launch_bounds__(256) void k_pass3(const float* __restrict__ x,
                                               const float* __restrict__ cons,
                                               const float* __restrict__ Wc,
                                               float* __restrict__ y) {
    int gtid = blockIdx.x * 256 + threadIdx.x;
    int c = gtid & (CHANNELS - 1);
    int k = gtid >> 9;

    const float* cp = Wc + (size_t)k * NSTATE * CHANNELS + c;
    float h[NSTATE];
    #pragma unroll
    for (int n = 0; n < NSTATE; ++n) h[n] = cp[(size_t)n * CHANNELS];

    const float* xp = x + (size_t)k * TCHUNK * CHANNELS + c;
    float*       yp = y + (size_t)k * TCHUNK * CHANNELS + c;

    float xv = xp[0];
    #pragma unroll 1
    for (int tau = 0; tau < TCHUNK; ++tau) {
        float xn = (tau + 1 < TCHUNK) ? xp[(size_t)(tau + 1) * CHANNELS] : 0.f;
        float y0 = 0.f, y1 = 0.f, y2 = 0.f, y3 = 0.f;
        #pragma unroll
        for (int n = 0; n < NSTATE; n += 4) {
            h[n]     = fmaf(cons[n],     h[n],     xv);
            h[n + 1] = fmaf(cons[n + 1], h[n + 1], xv);
            h[n + 2] = fmaf(cons[n + 2], h[n + 2], xv);
            h[n + 3] = fmaf(cons[n + 3], h[n + 3], xv);
            y0 = fmaf(cons[NSTATE + n],     h[n],     y0);
            y1 = fmaf(cons[NSTATE + n + 1], h[n + 1], y1);
            y2 = fmaf(cons[NSTATE + n + 2], h[n + 2], y2);
            y3 = fmaf(cons[NSTATE + n + 3], h[n + 3], y3);
        }
        yp[(size_t)tau * CHANNELS] = (y0 + y1) + (y2 + y3);
        xv = xn;
    }
}

// ---------------------------------------------------------------------------
// Fallback (only if ws is too small): one thread per channel, full scan.
// Slow but correct; needs no workspace.
// ---------------------------------------------------------------------------
__global__ __launch_bounds__(256) void k_fallback(const float* __restrict__ x,
                                                  const float* __restrict__ logA,
                                                  const float* __restrict__ B,
                                                  const float* __restrict__ C,
                                                  float* __restrict__ y) {
    int c = blockIdx.x * blockDim.x + threadIdx.x;
    if (c >= CHANNELS) return;
    float Abar[NSTATE], CB[NSTATE], h[NSTATE];
    for (int n = 0; n < NSTATE; ++n) {
        double A    = -exp((double)logA[n]);
        double ab   = exp(A * (1.0 / 4096.0));
        double Bbar = (ab - 1.0) * (double)B[n] / A;
        Abar[n] = (float)ab;
        CB[n]   = (float)((double)C[n] * Bbar);
        h[n]    = 0.f;
    }
    for (int t = 0; t < LENGTH; ++t) {
        float xv = x[(size_t)t * CHANNELS + c];
        float acc = 0.f;
        for (int n = 0; n < NSTATE; ++n) {
            h[n] = fmaf(Abar[n], h[n], xv);
            acc  = fmaf(CB[n], h[n], acc);
        }
        y[(size_t)t * CHANNELS + c] = acc;
    }
}

extern "C" void kernel_launch(void* const* d_in, const int* in_sizes, int n_in,
                              void* d_out, int out_size, void* d_ws, size_t ws_size,
                              hipStream_t stream) {
    const float* x    = (const float*)d_in[0];
    const float* logA = (const float*)d_in[1];
    const float* B    = (const float*)d_in[2];
    const float* C    = (const float*)d_in[3];
    float* yout = (float*)d_out;

    size_t need = (size_t)(E_ELEMS + 3 * NSTATE) * sizeof(float);
    if (ws_size < need) {
        // Workspace too small for the chunked scan: correct-but-slow fallback.
        k_fallback<<<(CHANNELS + 255) / 256, 256, 0, stream>>>(x, logA, B, C, yout);
        return;
    }

    float* W    = (float*)d_ws;      // E / carry region: NCHUNK*NSTATE*CHANNELS
    float* cons = W + E_ELEMS;       // 192 floats of constants

    k_setup<<<1, 64, 0, stream>>>(logA, B, C, cons);
    k_pass1<<<(NCHUNK * CHANNELS) / 256, 256, 0, stream>>>(x, cons, W);
    k_pass2<<<(NSTATE * CHANNELS) / 256, 256, 0, stream>>>(W, cons);
    k_pass3<<<(NCHUNK * CHANNELS) / 256, 256, 0, stream>>>(x, cons, W, yout);
}

// Round 2
// 115.314 us; speedup vs baseline: 1.4410x; 1.4410x over previous
//
#include <hip/hip_runtime.h>
#include <math.h>

#define LENGTH   8192
#define CHANNELS 512
#define NSTATE   64
#define TCHUNK   64
#define NCHUNK   (LENGTH / TCHUNK)            /* 128 */
#define E_ELEMS  (NCHUNK * NSTATE * CHANNELS) /* 4,194,304 floats = 16 MB */

// ---------------------------------------------------------------------------
// Setup: Abar[n], CB[n] = C[n]*Bbar[n], AbarT[n] = Abar^TCHUNK  (fp64 precompute)
// Rescaled state h' = h / Bbar  =>  h' = Abar*h' + x ;  y = sum CB[n]*h'[n]
// ---------------------------------------------------------------------------
__global__ void k_setup(const float* __restrict__ logA, const float* __restrict__ B,
                        const float* __restrict__ C, float* __restrict__ cons) {
    int n = threadIdx.x;
    if (n < NSTATE) {
        double A    = -exp((double)logA[n]);
        double ab   = exp(A * (1.0 / 4096.0));       // Abar
        double Bbar = (ab - 1.0) * (double)B[n] / A;
        double abT  = ab;
        #pragma unroll
        for (int i = 0; i < 6; ++i) abT *= abT;      // ab^64 == ab^TCHUNK
        cons[n]              = (float)ab;
        cons[NSTATE + n]     = (float)((double)C[n] * Bbar);
        cons[2 * NSTATE + n] = (float)abT;
    }
}

// ---------------------------------------------------------------------------
// Pass 1: per (chunk k, channel c): local end-state from zero init.
// PF=8 x-rows prefetched; prefetch address is clamped (uniform scalar min),
// NOT selected on the loaded value, so vmcnt wait lands at use time.
// ---------------------------------------------------------------------------
#define PF1 8
__global__ __launch_bounds__(256, 1) void k_pass1(const float* __restrict__ x,
                                                  const float* __restrict__ cons,
                                                  float* __restrict__ E) {
    int gtid = blockIdx.x * 256 + threadIdx.x;
    int c = gtid & (CHANNELS - 1);
    int k = gtid >> 9;
    const float* xp = x + (size_t)k * TCHUNK * CHANNELS + c;

    float h[NSTATE];
    #pragma unroll
    for (int n = 0; n < NSTATE; ++n) h[n] = 0.f;

    float xbuf[PF1];
    #pragma unroll
    for (int j = 0; j < PF1; ++j) xbuf[j] = xp[(size_t)j * CHANNELS];

    #pragma unroll 1
    for (int t0 = 0; t0 < TCHUNK; t0 += PF1) {
        #pragma unroll
        for (int j = 0; j < PF1; ++j) {
            int nt = t0 + PF1 + j;
            if (nt > TCHUNK - 1) nt = TCHUNK - 1;   // uniform clamp, no data dep
            float xn = xp[(size_t)nt * CHANNELS];
            float xv = xbuf[j];
            #pragma unroll
            for (int n = 0; n < NSTATE; ++n) h[n] = fmaf(cons[n], h[n], xv);
            xbuf[j] = xn;
        }
    }

    float* Ep = E + (size_t)k * NSTATE * CHANNELS + c;
    #pragma unroll
    for (int n = 0; n < NSTATE; ++n) Ep[(size_t)n * CHANNELS] = h[n];
}

// ---------------------------------------------------------------------------
// Pass 2: per (state n, channel c): sequential carry scan over chunks, in
// place. Group-16 double-buffered loads, fully unrolled: 8 latency periods
// instead of 128. Loads of group g+1 (slots k0+16..k0+31) are issued before
// stores of group g (slots k0..k0+15) -> disjoint, in-place safe.
// ---------------------------------------------------------------------------
#define G2 16
__global__ __launch_bounds__(64, 1) void k_pass2(float* __restrict__ W,
                                                 const float* __restrict__ cons) {
    int gtid = blockIdx.x * 64 + threadIdx.x;
    int c = gtid & (CHANNELS - 1);
    int n = gtid >> 9;
    float aT = cons[2 * NSTATE + n];
    float* p = W + (size_t)n * CHANNELS + c;
    const size_t S = (size_t)NSTATE * CHANNELS;

    float e[2][G2];
    #pragma unroll
    for (int j = 0; j < G2; ++j) e[0][j] = p[(size_t)j * S];

    float hc = 0.f;
    #pragma unroll
    for (int k0 = 0; k0 < NCHUNK; k0 += G2) {
        const int cur = (k0 / G2) & 1;
        const int nxt = cur ^ 1;
        if (k0 + G2 < NCHUNK) {
            #pragma unroll
            for (int j = 0; j < G2; ++j) e[nxt][j] = p[(size_t)(k0 + G2 + j) * S];
        }
        #pragma unroll
        for (int j = 0; j < G2; ++j) {
            p[(size_t)(k0 + j) * S] = hc;
            hc = fmaf(aT, hc, e[cur][j]);
        }
    }
}

// ---------------------------------------------------------------------------
// Pass 3: per (chunk k, channel c): re-scan chunk from exact carry, emit y.
// PF=4 x-rows prefetched; 4-way split y accumulators.
// ---------------------------------------------------------------------------
#define PF3 4
__global__ __launch_bounds__(256, 1) void k_pass3(const float* __restrict__ x,
                                                  const float* __restrict__ cons,
                                                  const float* __restrict__ Wc,
                                                  float* __restrict__ y) {
    int gtid = blockIdx.x * 256 + threadIdx.x;
    int c = gtid & (CHANNELS - 1);
    int k = gtid >> 9;

    const float* cp = Wc + (size_t)k * NSTATE * CHANNELS + c;
    float h[NSTATE];
    #pragma unroll
    for (int n = 0; n < NSTATE; ++n) h[n] = cp[(size_t)n * CHANNELS];

    const float* xp = x + (size_t)k * TCHUNK * CHANNELS + c;
    float*       yp = y + (size_t)k * TCHUNK * CHANNELS + c;

    float xbuf[PF3];
    #pragma unroll
    for (int j = 0; j < PF3; ++j) xbuf[j] = xp[(size_t)j * CHANNELS];

    #pragma unroll 1
    for (int t0 = 0; t0 < TCHUNK; t0 += PF3) {
        #pragma unroll
        for (int j = 0; j < PF3; ++j) {
            int nt = t0 + PF3 + j;
            if (nt > TCHUNK - 1) nt = TCHUNK - 1;   // uniform clamp, no data dep
            float xn = xp[(size_t)nt * CHANNELS];
            float xv = xbuf[j];
            float y0 = 0.f, y1 = 0.f, y2 = 0.f, y3 = 0.f;
            #pragma unroll
            for (int n = 0; n < NSTATE; n += 4) {
                h[n]     = fmaf(cons[n],     h[n],     xv);
                h[n + 1] = fmaf(cons[n + 1], h[n + 1], xv);
                h[n + 2] = fmaf(cons[n + 2], h[n + 2], xv);
                h[n + 3] = fmaf(cons[n + 3], h[n + 3], xv);
                y0 = fmaf(cons[NSTATE + n],     h[n],     y0);
                y1 = fmaf(cons[NSTATE + n + 1], h[n + 1], y1);
                y2 = fmaf(cons[NSTATE + n + 2], h[n + 2], y2);
                y3 = fmaf(cons[NSTATE + n + 3], h[n + 3], y3);
            }
            yp[(size_t)(t0 + j) * CHANNELS] = (y0 + y1) + (y2 + y3);
            xbuf[j] = xn;
        }
    }
}

// ---------------------------------------------------------------------------
// Fallback (only if ws is too small): one thread per channel, full scan.
// ---------------------------------------------------------------------------
__global__ __launch_bounds__(256) void k_fallback(const float* __restrict__ x,
                                                  const float* __restrict__ logA,
                                                  const float* __restrict__ B,
                                                  const float* __restrict__ C,
                                                  float* __restrict__ y) {
    int c = blockIdx.x * blockDim.x + threadIdx.x;
    if (c >= CHANNELS) return;
    float Abar[NSTATE], CB[NSTATE], h[NSTATE];
    for (int n = 0; n < NSTATE; ++n) {
        double A    = -exp((double)logA[n]);
        double ab   = exp(A * (1.0 / 4096.0));
        double Bbar = (ab - 1.0) * (double)B[n] / A;
        Abar[n] = (float)ab;
        CB[n]   = (float)((double)C[n] * Bbar);
        h[n]    = 0.f;
    }
    for (int t = 0; t < LENGTH; ++t) {
        float xv = x[(size_t)t * CHANNELS + c];
        float acc = 0.f;
        for (int n = 0; n < NSTATE; ++n) {
            h[n] = fmaf(Abar[n], h[n], xv);
            acc  = fmaf(CB[n], h[n], acc);
        }
        y[(size_t)t * CHANNELS + c] = acc;
    }
}

extern "C" void kernel_launch(void* const* d_in, const int* in_sizes, int n_in,
                              void* d_out, int out_size, void* d_ws, size_t ws_size,
                              hipStream_t stream) {
    const float* x    = (const float*)d_in[0];
    const float* logA = (const float*)d_in[1];
    const float* B    = (const float*)d_in[2];
    const float* C    = (const float*)d_in[3];
    float* yout = (float*)d_out;

    size_t need = (size_t)(E_ELEMS + 3 * NSTATE) * sizeof(float);
    if (ws_size < need) {
        k_fallback<<<(CHANNELS + 255) / 256, 256, 0, stream>>>(x, logA, B, C, yout);
        return;
    }

    float* W    = (float*)d_ws;      // E / carry region: NCHUNK*NSTATE*CHANNELS
    float* cons = W + E_ELEMS;       // 192 floats of constants

    k_setup<<<1, 64, 0, stream>>>(logA, B, C, cons);
    k_pass1<<<(NCHUNK * CHANNELS) / 256, 256, 0, stream>>>(x, cons, W);
    k_pass2<<<(NSTATE * CHANNELS) / 64, 64, 0, stream>>>(W, cons);
    k_pass3<<<(NCHUNK * CHANNELS) / 256, 256, 0, stream>>>(x, cons, W, yout);
}

// Round 3
// 113.881 us; speedup vs baseline: 1.4592x; 1.0126x over previous
//
#include <hip/hip_runtime.h>
#include <math.h>

#define LENGTH   8192
#define CHANNELS 512
#define NSTATE   64
#define TCHUNK   64
#define NCHUNK   (LENGTH / TCHUNK)            /* 128 */
#define E_ELEMS  (NCHUNK * NSTATE * CHANNELS) /* 4,194,304 floats = 16 MB */

// ws layout (floats): W[E_ELEMS] | cons[192] | Gt[4096] | Tt[4096] | Pt[4096]
//   cons: [Abar | CB | AbarT]  (pass2 only)
//   Gt[s][n] = Abar_n^(63-s)            (pass1:  E_k = G @ X_k)
//   Tt[s][t] = (t>=s) ? K[t-s] : 0      (pass3:  Y_k = T @ X_k + P @ Hc_k)
//   Pt[n][t] = CB_n * Abar_n^(t+1)
// Rescaled state h' = h / Bbar  =>  h' = Abar*h' + x ;  y = sum CB[n]*h'[n]

// ---------------------------------------------------------------------------
// Setup (1 block, 64 threads): all constants in fp64.
// ---------------------------------------------------------------------------
__global__ void k_setup(const float* __restrict__ logA, const float* __restrict__ B,
                        const float* __restrict__ C, float* __restrict__ cons,
                        float* __restrict__ Gt, float* __restrict__ Tt,
                        float* __restrict__ Pt) {
    __shared__ double contrib[64][65];   // contrib[n][d] = CB_n * Abar_n^d
    __shared__ double Kd[64];
    int n = threadIdx.x;                 // 64 threads

    double A    = -exp((double)logA[n]);
    double ab   = exp(A * (1.0 / 4096.0));
    double Bbar = (ab - 1.0) * (double)B[n] / A;
    double CB   = (double)C[n] * Bbar;

    cons[n]       = (float)ab;
    cons[64 + n]  = (float)CB;
    cons[128 + n] = (float)exp(A * (64.0 / 4096.0));   // Abar^TCHUNK

    double p = 1.0;                       // ab^e
    #pragma unroll 1
    for (int e = 0; e < 64; ++e) { Gt[(63 - e) * 64 + n] = (float)p; p *= ab; }

    p = ab;                               // ab^(t+1)
    #pragma unroll 1
    for (int t = 0; t < 64; ++t) { Pt[n * 64 + t] = (float)(CB * p); p *= ab; }

    p = CB;                               // CB * ab^d
    #pragma unroll 1
    for (int d = 0; d < 64; ++d) { contrib[n][d] = p; p *= ab; }
    __syncthreads();

    double Ksum = 0.0;                    // K[d] = sum_n CB_n ab_n^d
    #pragma unroll 1
    for (int m = 0; m < 64; ++m) Ksum += contrib[m][n];
    Kd[n] = Ksum;
    __syncthreads();

    int s = n;                            // Tt row s
    #pragma unroll 1
    for (int t = 0; t < 64; ++t) Tt[s * 64 + t] = (t >= s) ? (float)Kd[t - s] : 0.f;
}

// ---------------------------------------------------------------------------
// Pass 1 (GEMM): block = (chunk k, 64-channel tile). E_k[n][c] = sum_s G[n][s] X[s][c].
// Wave w owns 16 n-rows; lane = c. Gt rows are wave-uniform 16-float strips.
// ---------------------------------------------------------------------------
__global__ __launch_bounds__(256, 4) void k_pass1(const float* __restrict__ x,
                                                  const float* __restrict__ Gt,
                                                  float* __restrict__ E) {
    __shared__ float Xl[64 * 64];
    int tid = threadIdx.x;
    int k   = blockIdx.x >> 3;
    int c0  = (blockIdx.x & 7) * 64;

    const float* xsrc = x + (size_t)k * TCHUNK * CHANNELS + c0;
    #pragma unroll
    for (int i = 0; i < 4; ++i) {
        int idx = tid + 256 * i;          // 1024 float4s
        int s   = idx >> 4;
        int cq  = (idx & 15) * 4;
        *(float4*)&Xl[s * 64 + cq] = *(const float4*)(xsrc + (size_t)s * CHANNELS + cq);
    }
    __syncthreads();

    int w    = __builtin_amdgcn_readfirstlane(tid >> 6);
    int lane = tid & 63;
    const float* Gw = Gt + 16 * w;        // Gt[s][16w .. 16w+16)

    float acc[16];
    #pragma unroll
    for (int j = 0; j < 16; ++j) acc[j] = 0.f;

    #pragma unroll 4
    for (int s = 0; s < 64; ++s) {
        float xv = Xl[s * 64 + lane];
        const float* g = Gw + s * 64;
        #pragma unroll
        for (int j = 0; j < 16; ++j) acc[j] = fmaf(g[j], xv, acc[j]);
    }

    float* Ep = E + ((size_t)k * NSTATE + 16 * w) * CHANNELS + c0 + lane;
    #pragma unroll
    for (int j = 0; j < 16; ++j) Ep[(size_t)j * CHANNELS] = acc[j];
}

// ---------------------------------------------------------------------------
// Pass 2: per (state n, channel c): sequential carry scan over chunks, in
// place, group-16 double-buffered. carry entering chunk k lands in slot k.
// ---------------------------------------------------------------------------
#define G2 16
__global__ __launch_bounds__(64, 1) void k_pass2(float* __restrict__ W,
                                                 const float* __restrict__ cons) {
    int gtid = blockIdx.x * 64 + threadIdx.x;
    int c = gtid & (CHANNELS - 1);
    int n = gtid >> 9;
    float aT = cons[128 + n];
    float* p = W + (size_t)n * CHANNELS + c;
    const size_t S = (size_t)NSTATE * CHANNELS;

    float e[2][G2];
    #pragma unroll
    for (int j = 0; j < G2; ++j) e[0][j] = p[(size_t)j * S];

    float hc = 0.f;
    #pragma unroll
    for (int k0 = 0; k0 < NCHUNK; k0 += G2) {
        const int cur = (k0 / G2) & 1;
        const int nxt = cur ^ 1;
        if (k0 + G2 < NCHUNK) {
            #pragma unroll
            for (int j = 0; j < G2; ++j) e[nxt][j] = p[(size_t)(k0 + G2 + j) * S];
        }
        #pragma unroll
        for (int j = 0; j < G2; ++j) {
            p[(size_t)(k0 + j) * S] = hc;
            hc = fmaf(aT, hc, e[cur][j]);
        }
    }
}

// ---------------------------------------------------------------------------
// Pass 3 (two GEMMs): Y_k[t][c] = sum_s T[t][s] X[s][c] + sum_n P[t][n] Hc[n][c].
// Wave w owns 16 taus; lane = c. Tt/Pt strips are wave-uniform.
// ---------------------------------------------------------------------------
__global__ __launch_bounds__(256, 4) void k_pass3(const float* __restrict__ x,
                                                  const float* __restrict__ Tt,
                                                  const float* __restrict__ Pt,
                                                  const float* __restrict__ Wc,
                                                  float* __restrict__ y) {
    __shared__ float Xl[64 * 64];
    __shared__ float Hl[64 * 64];
    int tid = threadIdx.x;
    int k   = blockIdx.x >> 3;
    int c0  = (blockIdx.x & 7) * 64;

    const float* xsrc = x  + (size_t)k * TCHUNK * CHANNELS + c0;
    const float* hsrc = Wc + (size_t)k * NSTATE * CHANNELS + c0;
    #pragma unroll
    for (int i = 0; i < 4; ++i) {
        int idx = tid + 256 * i;
        int s   = idx >> 4;
        int cq  = (idx & 15) * 4;
        *(float4*)&Xl[s * 64 + cq] = *(const float4*)(xsrc + (size_t)s * CHANNELS + cq);
        *(float4*)&Hl[s * 64 + cq] = *(const float4*)(hsrc + (size_t)s * CHANNELS + cq);
    }
    __syncthreads();

    int w    = __builtin_amdgcn_readfirstlane(tid >> 6);
    int lane = tid & 63;
    int t0   = 16 * w;

    float acc[16];
    #pragma unroll
    for (int j = 0; j < 16; ++j) acc[j] = 0.f;

    const float* Tw = Tt + t0;            // Tt[s][t0 .. t0+16)
    #pragma unroll 4
    for (int s = 0; s < 64; ++s) {
        float xv = Xl[s * 64 + lane];
        const float* tt = Tw + s * 64;
        #pragma unroll
        for (int j = 0; j < 16; ++j) acc[j] = fmaf(tt[j], xv, acc[j]);
    }

    const float* Pw = Pt + t0;            // Pt[n][t0 .. t0+16)
    #pragma unroll 4
    for (int n = 0; n < 64; ++n) {
        float hv = Hl[n * 64 + lane];
        const float* pp = Pw + n * 64;
        #pragma unroll
        for (int j = 0; j < 16; ++j) acc[j] = fmaf(pp[j], hv, acc[j]);
    }

    float* yp = y + ((size_t)k * TCHUNK + t0) * CHANNELS + c0 + lane;
    #pragma unroll
    for (int j = 0; j < 16; ++j) yp[(size_t)j * CHANNELS] = acc[j];
}

// ---------------------------------------------------------------------------
// Fallback (only if ws is too small): one thread per channel, full scan.
// ---------------------------------------------------------------------------
__global__ __launch_bounds__(256) void k_fallback(const float* __restrict__ x,
                                                  const float* __restrict__ logA,
                                                  const float* __restrict__ B,
                                                  const float* __restrict__ C,
                                                  float* __restrict__ y) {
    int c = blockIdx.x * blockDim.x + threadIdx.x;
    if (c >= CHANNELS) return;
    float Abar[NSTATE], CB[NSTATE], h[NSTATE];
    for (int n = 0; n < NSTATE; ++n) {
        double A    = -exp((double)logA[n]);
        double ab   = exp(A * (1.0 / 4096.0));
        double Bbar = (ab - 1.0) * (double)B[n] / A;
        Abar[n] = (float)ab;
        CB[n]   = (float)((double)C[n] * Bbar);
        h[n]    = 0.f;
    }
    for (int t = 0; t < LENGTH; ++t) {
        float xv = x[(size_t)t * CHANNELS + c];
        float acc = 0.f;
        for (int n = 0; n < NSTATE; ++n) {
            h[n] = fmaf(Abar[n], h[n], xv);
            acc  = fmaf(CB[n], h[n], acc);
        }
        y[(size_t)t * CHANNELS + c] = acc;
    }
}

extern "C" void kernel_launch(void* const* d_in, const int* in_sizes, int n_in,
                              void* d_out, int out_size, void* d_ws, size_t ws_size,
                              hipStream_t stream) {
    const float* x    = (const float*)d_in[0];
    const float* logA = (const float*)d_in[1];
    const float* B    = (const float*)d_in[2];
    const float* C    = (const float*)d_in[3];
    float* yout = (float*)d_out;

    size_t need = (size_t)(E_ELEMS + 192 + 3 * 4096) * sizeof(float);
    if (ws_size < need) {
        k_fallback<<<(CHANNELS + 255) / 256, 256, 0, stream>>>(x, logA, B, C, yout);
        return;
    }

    float* W    = (float*)d_ws;          // E / carry region
    float* cons = W + E_ELEMS;           // 192
    float* Gt   = cons + 192;            // 4096
    float* Tt   = Gt + 4096;             // 4096
    float* Pt   = Tt + 4096;             // 4096

    k_setup<<<1, 64, 0, stream>>>(logA, B, C, cons, Gt, Tt, Pt);
    k_pass1<<<NCHUNK * 8, 256, 0, stream>>>(x, Gt, W);
    k_pass2<<<(NSTATE * CHANNELS) / 64, 64, 0, stream>>>(W, cons);
    k_pass3<<<NCHUNK * 8, 256, 0, stream>>>(x, Tt, Pt, W, yout);
}

// Round 4
// 108.956 us; speedup vs baseline: 1.5251x; 1.0452x over previous
//
#include <hip/hip_runtime.h>
#include <math.h>

#define LENGTH   8192
#define CHANNELS 512
#define NSTATE   64
#define TCHUNK   64
#define NCHUNK   (LENGTH / TCHUNK)            /* 128 */
#define E_ELEMS  (NCHUNK * NSTATE * CHANNELS) /* 16 MB: E / carry buffer in ws */
#define LOG2E    1.4426950408889634f
#define DT       (1.0f / 4096.0f)

// Math (rescaled state h' = h/Bbar):  h'_t = Abar*h'_{t-1} + x_t ; y = sum_n CB_n h'_n
//   Abar_n = exp(A_n*dt), A_n = -exp(logA_n), CB_n = C_n*Bbar_n, Bbar = expm1(A*dt)*B/A
// Chunked (T=64):
//   pass1: E_k[n][c]   = sum_s Abar_n^(63-s) x[kT+s][c]          (G @ X_k)
//   pass2: carry[k]    = Abar^T*carry[k-1] + E[k-1], carry[0]=0   (serial over k, in place)
//   pass3: y[kT+t][c]  = sum_{s<=t} K[t-s] x[kT+s][c] + sum_n CB_n Abar_n^(t+1) carry_k[n][c]
//          K[d] = sum_n CB_n Abar_n^d   (Toeplitz @ X_k  +  P @ Hc_k)
// All constants computed per-block in fp32 (exp2f); rel err ~1e-7 << threshold headroom.

// ---------------------------------------------------------------------------
// Pass 1: block = (chunk k, 64-ch tile). 4x4 register blocking, X & G in LDS.
// ---------------------------------------------------------------------------
__global__ __launch_bounds__(256, 4) void k_pass1(const float* __restrict__ x,
                                                  const float* __restrict__ logA,
                                                  float* __restrict__ E) {
    __shared__ float Xl[64 * 64];
    __shared__ float Gl[64 * 64];   // Gl[s][n] = Abar_n^(63-s)
    __shared__ float l2ab[64];
    int tid = threadIdx.x;
    int k   = blockIdx.x >> 3;
    int c0g = (blockIdx.x & 7) * 64;

    if (tid < 64) {
        float A = -expf(logA[tid]);
        l2ab[tid] = A * DT * LOG2E;          // log2(Abar)
    }
    const float* xsrc = x + (size_t)k * TCHUNK * CHANNELS + c0g;
    #pragma unroll
    for (int i = 0; i < 4; ++i) {
        int idx = tid + 256 * i;
        int s = idx >> 4, cq = (idx & 15) * 4;
        *(float4*)&Xl[s * 64 + cq] = *(const float4*)(xsrc + (size_t)s * CHANNELS + cq);
    }
    __syncthreads();
    {
        int s = tid >> 2, nb = (tid & 3) * 16;
        float e = (float)(63 - s);
        #pragma unroll
        for (int j = 0; j < 16; ++j) Gl[s * 64 + nb + j] = exp2f(e * l2ab[nb + j]);
    }
    __syncthreads();

    int c0 = (tid & 15) * 4;
    int n0 = (tid >> 4) * 4;
    float a00=0,a01=0,a02=0,a03=0, a10=0,a11=0,a12=0,a13=0;
    float a20=0,a21=0,a22=0,a23=0, a30=0,a31=0,a32=0,a33=0;

    #pragma unroll 8
    for (int s = 0; s < 64; ++s) {
        float4 xv = *(const float4*)&Xl[s * 64 + c0];
        float4 gv = *(const float4*)&Gl[s * 64 + n0];
        a00 = fmaf(gv.x, xv.x, a00); a01 = fmaf(gv.x, xv.y, a01);
        a02 = fmaf(gv.x, xv.z, a02); a03 = fmaf(gv.x, xv.w, a03);
        a10 = fmaf(gv.y, xv.x, a10); a11 = fmaf(gv.y, xv.y, a11);
        a12 = fmaf(gv.y, xv.z, a12); a13 = fmaf(gv.y, xv.w, a13);
        a20 = fmaf(gv.z, xv.x, a20); a21 = fmaf(gv.z, xv.y, a21);
        a22 = fmaf(gv.z, xv.z, a22); a23 = fmaf(gv.z, xv.w, a23);
        a30 = fmaf(gv.w, xv.x, a30); a31 = fmaf(gv.w, xv.y, a31);
        a32 = fmaf(gv.w, xv.z, a32); a33 = fmaf(gv.w, xv.w, a33);
    }

    float* Ep = E + ((size_t)k * NSTATE + n0) * CHANNELS + c0g + c0;
    *(float4*)(Ep)                    = make_float4(a00, a01, a02, a03);
    *(float4*)(Ep + 1 * CHANNELS)     = make_float4(a10, a11, a12, a13);
    *(float4*)(Ep + 2 * CHANNELS)     = make_float4(a20, a21, a22, a23);
    *(float4*)(Ep + 3 * CHANNELS)     = make_float4(a30, a31, a32, a33);
}

// ---------------------------------------------------------------------------
// Pass 2: per (state n, channel c): serial carry scan over chunks, in place,
// group-16 double-buffered. n is block-uniform -> aT scalar.
// ---------------------------------------------------------------------------
#define G2 16
__global__ __launch_bounds__(64, 1) void k_pass2(float* __restrict__ W,
                                                 const float* __restrict__ logA) {
    int gtid = blockIdx.x * 64 + threadIdx.x;
    int c = gtid & (CHANNELS - 1);
    int n = gtid >> 9;
    float A  = -expf(logA[n]);
    float aT = exp2f(A * (64.0f * DT) * LOG2E);   // Abar^TCHUNK
    float* p = W + (size_t)n * CHANNELS + c;
    const size_t S = (size_t)NSTATE * CHANNELS;

    float e[2][G2];
    #pragma unroll
    for (int j = 0; j < G2; ++j) e[0][j] = p[(size_t)j * S];

    float hc = 0.f;
    #pragma unroll
    for (int k0 = 0; k0 < NCHUNK; k0 += G2) {
        const int cur = (k0 / G2) & 1;
        const int nxt = cur ^ 1;
        if (k0 + G2 < NCHUNK) {
            #pragma unroll
            for (int j = 0; j < G2; ++j) e[nxt][j] = p[(size_t)(k0 + G2 + j) * S];
        }
        #pragma unroll
        for (int j = 0; j < G2; ++j) {
            p[(size_t)(k0 + j) * S] = hc;
            hc = fmaf(aT, hc, e[cur][j]);
        }
    }
}

// ---------------------------------------------------------------------------
// Pass 3: block = (chunk k, 64-ch tile). Y = T@X + P@Hc, 4x4 register blocking.
// T (Toeplitz of K), P, X, Hc all staged in LDS (~67 KB -> 2 blocks/CU).
// ---------------------------------------------------------------------------
__global__ __launch_bounds__(256, 2) void k_pass3(const float* __restrict__ x,
                                                  const float* __restrict__ logA,
                                                  const float* __restrict__ Bv,
                                                  const float* __restrict__ Cv,
                                                  const float* __restrict__ Wc,
                                                  float* __restrict__ y) {
    __shared__ float Xl[64 * 64];
    __shared__ float Hl[64 * 64];
    __shared__ float Tl[64 * 64];   // Tl[s][t] = (t>=s) ? K[t-s] : 0
    __shared__ float Pl[64 * 64];   // Pl[n][t] = CB_n * Abar_n^(t+1)
    __shared__ float l2ab[64], CBl[64], Kl[64], Kpart[4 * 64];
    int tid = threadIdx.x;
    int k   = blockIdx.x >> 3;
    int c0g = (blockIdx.x & 7) * 64;

    if (tid < 64) {
        int n = tid;
        float A    = -expf(logA[n]);
        float Bbar = expm1f(A * DT) * Bv[n] / A;
        l2ab[n] = A * DT * LOG2E;
        CBl[n]  = Cv[n] * Bbar;
    }
    const float* xsrc = x  + (size_t)k * TCHUNK * CHANNELS + c0g;
    const float* hsrc = Wc + (size_t)k * NSTATE * CHANNELS + c0g;
    #pragma unroll
    for (int i = 0; i < 4; ++i) {
        int idx = tid + 256 * i;
        int s = idx >> 4, cq = (idx & 15) * 4;
        *(float4*)&Xl[s * 64 + cq] = *(const float4*)(xsrc + (size_t)s * CHANNELS + cq);
        *(float4*)&Hl[s * 64 + cq] = *(const float4*)(hsrc + (size_t)s * CHANNELS + cq);
    }
    __syncthreads();
    {   // Pl: 16 entries per thread
        int n = tid >> 2, tb = (tid & 3) * 16;
        float l2 = l2ab[n], cb = CBl[n];
        #pragma unroll
        for (int j = 0; j < 16; ++j)
            Pl[n * 64 + tb + j] = cb * exp2f((float)(tb + j + 1) * l2);
    }
    {   // K partials: thread (d = tid&63, q = tid>>6) sums 16 states
        int d = tid & 63, q = tid >> 6;
        float s = 0.f;
        #pragma unroll
        for (int i = 0; i < 16; ++i) {
            int n = q * 16 + i;
            s = fmaf(CBl[n], exp2f((float)d * l2ab[n]), s);
        }
        Kpart[q * 64 + d] = s;
    }
    __syncthreads();
    if (tid < 64)
        Kl[tid] = (Kpart[tid] + Kpart[64 + tid]) + (Kpart[128 + tid] + Kpart[192 + tid]);
    __syncthreads();
    {   // Tl: 16 entries per thread
        int s = tid >> 2, tb = (tid & 3) * 16;
        #pragma unroll
        for (int j = 0; j < 16; ++j) {
            int t = tb + j;
            Tl[s * 64 + t] = (t >= s) ? Kl[t - s] : 0.f;
        }
    }
    __syncthreads();

    int c0 = (tid & 15) * 4;
    int t0 = (tid >> 4) * 4;
    float a00=0,a01=0,a02=0,a03=0, a10=0,a11=0,a12=0,a13=0;
    float a20=0,a21=0,a22=0,a23=0, a30=0,a31=0,a32=0,a33=0;

    #pragma unroll 4
    for (int s = 0; s < 64; ++s) {
        float4 xv = *(const float4*)&Xl[s * 64 + c0];
        float4 tv = *(const float4*)&Tl[s * 64 + t0];
        a00 = fmaf(tv.x, xv.x, a00); a01 = fmaf(tv.x, xv.y, a01);
        a02 = fmaf(tv.x, xv.z, a02); a03 = fmaf(tv.x, xv.w, a03);
        a10 = fmaf(tv.y, xv.x, a10); a11 = fmaf(tv.y, xv.y, a11);
        a12 = fmaf(tv.y, xv.z, a12); a13 = fmaf(tv.y, xv.w, a13);
        a20 = fmaf(tv.z, xv.x, a20); a21 = fmaf(tv.z, xv.y, a21);
        a22 = fmaf(tv.z, xv.z, a22); a23 = fmaf(tv.z, xv.w, a23);
        a30 = fmaf(tv.w, xv.x, a30); a31 = fmaf(tv.w, xv.y, a31);
        a32 = fmaf(tv.w, xv.z, a32); a33 = fmaf(tv.w, xv.w, a33);
    }
    #pragma unroll 4
    for (int n = 0; n < 64; ++n) {
        float4 hv = *(const float4*)&Hl[n * 64 + c0];
        float4 pv = *(const float4*)&Pl[n * 64 + t0];
        a00 = fmaf(pv.x, hv.x, a00); a01 = fmaf(pv.x, hv.y, a01);
        a02 = fmaf(pv.x, hv.z, a02); a03 = fmaf(pv.x, hv.w, a03);
        a10 = fmaf(pv.y, hv.x, a10); a11 = fmaf(pv.y, hv.y, a11);
        a12 = fmaf(pv.y, hv.z, a12); a13 = fmaf(pv.y, hv.w, a13);
        a20 = fmaf(pv.z, hv.x, a20); a21 = fmaf(pv.z, hv.y, a21);
        a22 = fmaf(pv.z, hv.z, a22); a23 = fmaf(pv.z, hv.w, a23);
        a30 = fmaf(pv.w, hv.x, a30); a31 = fmaf(pv.w, hv.y, a31);
        a32 = fmaf(pv.w, hv.z, a32); a33 = fmaf(pv.w, hv.w, a33);
    }

    float* yp = y + ((size_t)k * TCHUNK + t0) * CHANNELS + c0g + c0;
    *(float4*)(yp)                = make_float4(a00, a01, a02, a03);
    *(float4*)(yp + 1 * CHANNELS) = make_float4(a10, a11, a12, a13);
    *(float4*)(yp + 2 * CHANNELS) = make_float4(a20, a21, a22, a23);
    *(float4*)(yp + 3 * CHANNELS) = make_float4(a30, a31, a32, a33);
}

// ---------------------------------------------------------------------------
// Fallback (only if ws is too small): one thread per channel, full scan.
// ---------------------------------------------------------------------------
__global__ __launch_bounds__(256) void k_fallback(const float* __restrict__ x,
                                                  const float* __restrict__ logA,
                                                  const float* __restrict__ B,
                                                  const float* __restrict__ C,
                                                  float* __restrict__ y) {
    int c = blockIdx.x * blockDim.x + threadIdx.x;
    if (c >= CHANNELS) return;
    float Abar[NSTATE], CB[NSTATE], h[NSTATE];
    for (int n = 0; n < NSTATE; ++n) {
        float A    = -expf(logA[n]);
        float ab   = exp2f(A * DT * LOG2E);
        float Bbar = expm1f(A * DT) * B[n] / A;
        Abar[n] = ab;
        CB[n]   = C[n] * Bbar;
        h[n]    = 0.f;
    }
    for (int t = 0; t < LENGTH; ++t) {
        float xv = x[(size_t)t * CHANNELS + c];
        float acc = 0.f;
        for (int n = 0; n < NSTATE; ++n) {
            h[n] = fmaf(Abar[n], h[n], xv);
            acc  = fmaf(CB[n], h[n], acc);
        }
        y[(size_t)t * CHANNELS + c] = acc;
    }
}

extern "C" void kernel_launch(void* const* d_in, const int* in_sizes, int n_in,
                              void* d_out, int out_size, void* d_ws, size_t ws_size,
                              hipStream_t stream) {
    const float* x    = (const float*)d_in[0];
    const float* logA = (const float*)d_in[1];
    const float* B    = (const float*)d_in[2];
    const float* C    = (const float*)d_in[3];
    float* yout = (float*)d_out;

    if (ws_size < (size_t)E_ELEMS * sizeof(float)) {
        k_fallback<<<(CHANNELS + 255) / 256, 256, 0, stream>>>(x, logA, B, C, yout);
        return;
    }
    float* W = (float*)d_ws;   // E / carry buffer, 16 MB

    k_pass1<<<NCHUNK * 8, 256, 0, stream>>>(x, logA, W);
    k_pass2<<<(NSTATE * CHANNELS) / 64, 64, 0, stream>>>(W, logA);
    k_pass3<<<NCHUNK * 8, 256, 0, stream>>>(x, logA, B, C, W, yout);
}